// Round 2
// baseline (408.347 us; speedup 1.0000x reference)
//
#include <hip/hip_runtime.h>

// ---------------------------------------------------------------------------
// GCN layer: out[b][f][t][n] = relu( rsqrt(deg_in[n]) *
//     sum_{e: dst[e]=n} ( rsqrt(deg_out[src[e]]) * x[src[e]] @ W )[b][t][f] + bias[f] )
// Strategy: (1) degrees+CSR, (2) fused transpose+GEMM -> y[n][512] node-major,
//           (3) CSR gather-sum + epilogue + transpose-back.
// R1: aggregate tile 32->16 nodes (LDS 66->33KB, occupancy 18->~50%),
//     edge loop unroll 4; transform processes 2 bt per phase.
// ---------------------------------------------------------------------------

extern "C" __global__ void k_zero(int* __restrict__ p, int n) {
  int i = blockIdx.x * blockDim.x + threadIdx.x;
  if (i < n) p[i] = 0;
}

extern "C" __global__ void k_deg(const int* __restrict__ src, const int* __restrict__ dst,
                                 int* __restrict__ deg_out, int* __restrict__ deg_in, int E) {
  int e = blockIdx.x * blockDim.x + threadIdx.x;
  if (e < E) {
    atomicAdd(&deg_out[src[e]], 1);
    atomicAdd(&deg_in[dst[e]], 1);
  }
}

extern "C" __global__ void k_rsqrt(const int* __restrict__ dgo, const int* __restrict__ dgi,
                                   float* __restrict__ rs_out, float* __restrict__ rs_in, int N) {
  int i = blockIdx.x * blockDim.x + threadIdx.x;
  if (i < N) {
    int a = dgo[i] > 1 ? dgo[i] : 1;
    int b = dgi[i] > 1 ? dgi[i] : 1;
    rs_out[i] = rsqrtf((float)a);
    rs_in[i]  = rsqrtf((float)b);
  }
}

extern "C" __global__ __launch_bounds__(1024) void k_scan(const int* __restrict__ deg,
                                                          int* __restrict__ offs, int N) {
  __shared__ int part[1024];
  int tid = threadIdx.x;
  int chunk = (N + 1023) >> 10;
  int lo = tid * chunk;
  int hi = lo + chunk; if (hi > N) hi = N;
  int s = 0;
  for (int i = lo; i < hi; ++i) s += deg[i];
  part[tid] = s;
  __syncthreads();
  for (int off = 1; off < 1024; off <<= 1) {
    int v = part[tid];
    if (tid >= off) v += part[tid - off];
    __syncthreads();
    part[tid] = v;
    __syncthreads();
  }
  int run = (tid > 0) ? part[tid - 1] : 0;
  for (int i = lo; i < hi; ++i) { offs[i] = run; run += deg[i]; }
  if (tid == 1023) offs[N] = part[1023];
}

extern "C" __global__ void k_scatter(const int* __restrict__ src, const int* __restrict__ dst,
                                     const int* __restrict__ offs, int* __restrict__ cursor,
                                     int* __restrict__ csr_src, int E) {
  int e = blockIdx.x * blockDim.x + threadIdx.x;
  if (e < E) {
    int d = dst[e];
    int pos = offs[d] + atomicAdd(&cursor[d], 1);
    csr_src[pos] = src[e];
  }
}

// y[n][(b*4+t)*64 + f] = rs_out[n] * sum_h in_feat[((b*64+h)*4+t)*N + n] * W[h*64+f]
extern "C" __global__ __launch_bounds__(256) void k_transform(
    const float* __restrict__ in_feat, const float* __restrict__ W,
    const float* __restrict__ rs_out, float* __restrict__ y, int N) {
  __shared__ float Wl[4096];
  __shared__ float tile[2][4096];  // [pair][h=64][n=64]
  int tid = threadIdx.x;
  for (int i = tid; i < 4096; i += 256) Wl[i] = W[i];
  int n0 = blockIdx.x * 64;
  int nq = tid & 15;        // n quad: n = nq*4 .. nq*4+3
  int fq = tid >> 4;        // f quad: f = fq*4 .. fq*4+3
  int lrow = tid >> 6, lcol = tid & 63;
  __syncthreads();

  for (int bp = 0; bp < 4; ++bp) {   // bt = 2*bp, 2*bp+1
    // load tiles[0..1][h][n], channel-major coalesced 256B rows
    #pragma unroll
    for (int u = 0; u < 2; ++u) {
      int bt = bp * 2 + u;
      int b = bt >> 2, t = bt & 3;
      #pragma unroll
      for (int i = 0; i < 16; ++i) {
        int h = i * 4 + lrow;
        int n = n0 + lcol;
        float v = 0.0f;
        if (n < N) v = in_feat[(size_t)((b * 64 + h) * 4 + t) * (size_t)N + n];
        tile[u][h * 64 + lcol] = v;
      }
    }
    __syncthreads();

    float acc0[4][4], acc1[4][4];
    #pragma unroll
    for (int i = 0; i < 4; ++i)
      #pragma unroll
      for (int j = 0; j < 4; ++j) { acc0[i][j] = 0.0f; acc1[i][j] = 0.0f; }

    #pragma unroll 8
    for (int h = 0; h < 64; ++h) {
      float4 a0 = *(const float4*)&tile[0][h * 64 + nq * 4];
      float4 a1 = *(const float4*)&tile[1][h * 64 + nq * 4];
      float4 w  = *(const float4*)&Wl[h * 64 + fq * 4];
      float a0v[4] = {a0.x, a0.y, a0.z, a0.w};
      float a1v[4] = {a1.x, a1.y, a1.z, a1.w};
      float wv[4]  = {w.x, w.y, w.z, w.w};
      #pragma unroll
      for (int i = 0; i < 4; ++i)
        #pragma unroll
        for (int j = 0; j < 4; ++j) {
          acc0[i][j] = fmaf(a0v[i], wv[j], acc0[i][j]);
          acc1[i][j] = fmaf(a1v[i], wv[j], acc1[i][j]);
        }
    }

    #pragma unroll
    for (int i = 0; i < 4; ++i) {
      int n = n0 + nq * 4 + i;
      if (n < N) {
        float rs = rs_out[n];
        float4 o0, o1;
        o0.x = acc0[i][0] * rs; o0.y = acc0[i][1] * rs;
        o0.z = acc0[i][2] * rs; o0.w = acc0[i][3] * rs;
        o1.x = acc1[i][0] * rs; o1.y = acc1[i][1] * rs;
        o1.z = acc1[i][2] * rs; o1.w = acc1[i][3] * rs;
        *(float4*)&y[(size_t)n * 512 + (bp * 2 + 0) * 64 + fq * 4] = o0;
        *(float4*)&y[(size_t)n * 512 + (bp * 2 + 1) * 64 + fq * 4] = o1;
      }
    }
    __syncthreads();
  }
}

// out[((b*64+f)*4+t)*N + n] = relu( rs_in[n] * sum_{j in CSR(n)} y[csr_src[j]][c] + bias[f] )
extern "C" __global__ __launch_bounds__(256) void k_aggregate(
    const float* __restrict__ y, const int* __restrict__ offs,
    const int* __restrict__ csr_src, const float* __restrict__ rs_in,
    const float* __restrict__ bvec, float* __restrict__ out, int N) {
  __shared__ float agg[16 * 513];  // [node][channel], pad 513 -> conflict-free epilogue
  int tid = threadIdx.x;
  int lane = tid & 63, wave = tid >> 6;
  int n0 = blockIdx.x * 16;

  #pragma unroll
  for (int k = 0; k < 4; ++k) {
    int nl = k * 4 + wave;
    int n = n0 + nl;
    float4 accA = {0.f, 0.f, 0.f, 0.f};
    float4 accB = {0.f, 0.f, 0.f, 0.f};
    if (n < N) {
      int j0 = offs[n], j1 = offs[n + 1];
      int j = j0;
      for (; j + 3 < j1; j += 4) {
        int s0 = csr_src[j], s1 = csr_src[j + 1];
        int s2 = csr_src[j + 2], s3 = csr_src[j + 3];
        const float4* r0 = (const float4*)(y + (size_t)s0 * 512);
        const float4* r1 = (const float4*)(y + (size_t)s1 * 512);
        const float4* r2 = (const float4*)(y + (size_t)s2 * 512);
        const float4* r3 = (const float4*)(y + (size_t)s3 * 512);
        float4 a0 = r0[lane], a1 = r1[lane], a2 = r2[lane], a3 = r3[lane];
        float4 b0 = r0[64 + lane], b1 = r1[64 + lane];
        float4 b2 = r2[64 + lane], b3 = r3[64 + lane];
        accA.x += (a0.x + a1.x) + (a2.x + a3.x);
        accA.y += (a0.y + a1.y) + (a2.y + a3.y);
        accA.z += (a0.z + a1.z) + (a2.z + a3.z);
        accA.w += (a0.w + a1.w) + (a2.w + a3.w);
        accB.x += (b0.x + b1.x) + (b2.x + b3.x);
        accB.y += (b0.y + b1.y) + (b2.y + b3.y);
        accB.z += (b0.z + b1.z) + (b2.z + b3.z);
        accB.w += (b0.w + b1.w) + (b2.w + b3.w);
      }
      for (; j < j1; ++j) {
        int s0 = csr_src[j];
        const float4* r0 = (const float4*)(y + (size_t)s0 * 512);
        float4 a0 = r0[lane], b0 = r0[64 + lane];
        accA.x += a0.x; accA.y += a0.y; accA.z += a0.z; accA.w += a0.w;
        accB.x += b0.x; accB.y += b0.y; accB.z += b0.z; accB.w += b0.w;
      }
    }
    *(float4*)&agg[nl * 513 + lane * 4] = accA;
    *(float4*)&agg[nl * 513 + 256 + lane * 4] = accB;
  }
  __syncthreads();

  // epilogue: scale, bias, relu, transpose-back to channel-major
  int nl = tid & 15;
  int r0 = tid >> 4;  // 0..15
  int n = n0 + nl;
  float rs = (n < N) ? rs_in[n] : 0.0f;
  #pragma unroll 4
  for (int it = 0; it < 32; ++it) {
    int c = it * 16 + r0;          // c = (b*4+t)*64 + f
    float v = agg[nl * 513 + c];
    int f = c & 63, bt = c >> 6;
    int b = bt >> 2, t = bt & 3;
    v = v * rs + bvec[f];
    v = fmaxf(v, 0.0f);
    if (n < N) out[(size_t)((b * 64 + f) * 4 + t) * (size_t)N + n] = v;
  }
}

extern "C" void kernel_launch(void* const* d_in, const int* in_sizes, int n_in,
                              void* d_out, int out_size, void* d_ws, size_t ws_size,
                              hipStream_t stream) {
  const float* in_feat = (const float*)d_in[0];
  const int*   src     = (const int*)d_in[1];
  const int*   dst     = (const int*)d_in[2];
  const float* W       = (const float*)d_in[3];
  const float* bvec    = (const float*)d_in[4];
  float* out = (float*)d_out;

  int N = in_sizes[0] / 512;   // B*H*T = 2*64*4 = 512
  int E = in_sizes[1];

  int A  = (N + 64) & ~63;     // room for N+1 offsets, 64-aligned
  int EA = (E + 63) & ~63;

  // layout: the three arrays needing zero-init come first (one contiguous memset)
  int*   deg_out_i = (int*)d_ws;        // [A]  zeroed
  int*   deg_in_i  = deg_out_i + A;     // [A]  zeroed
  int*   cursor    = deg_in_i + A;      // [A]  zeroed
  int*   offs      = cursor + A;        // [A] (N+1 used, fully written by scan)
  float* rs_out    = (float*)(offs + A);
  float* rs_in     = rs_out + A;
  int*   csr_src   = (int*)(rs_in + A); // [EA]
  float* y         = (float*)(csr_src + EA); // [N*512]

  int z = 3 * A;
  hipLaunchKernelGGL(k_zero, dim3((z + 255) / 256), dim3(256), 0, stream, deg_out_i, z);
  hipLaunchKernelGGL(k_deg, dim3((E + 255) / 256), dim3(256), 0, stream,
                     src, dst, deg_out_i, deg_in_i, E);
  hipLaunchKernelGGL(k_rsqrt, dim3((N + 255) / 256), dim3(256), 0, stream,
                     deg_out_i, deg_in_i, rs_out, rs_in, N);
  hipLaunchKernelGGL(k_scan, dim3(1), dim3(1024), 0, stream, deg_in_i, offs, N);
  hipLaunchKernelGGL(k_scatter, dim3((E + 255) / 256), dim3(256), 0, stream,
                     src, dst, offs, cursor, csr_src, E);
  hipLaunchKernelGGL(k_transform, dim3((N + 63) / 64), dim3(256), 0, stream,
                     in_feat, W, rs_out, y, N);
  hipLaunchKernelGGL(k_aggregate, dim3((N + 15) / 16), dim3(256), 0, stream,
                     y, offs, csr_src, rs_in, bvec, out, N);
}

// Round 3
// 398.808 us; speedup vs baseline: 1.0239x; 1.0239x over previous
//
#include <hip/hip_runtime.h>

// ---------------------------------------------------------------------------
// GCN layer: out[b][f][t][n] = relu( rsqrt(deg_in[n]) *
//     sum_{e: dst[e]=n} ( rsqrt(deg_out[src[e]]) * x[src[e]] @ W )[b][t][f] + bias[f] )
// Strategy: (1) degrees+CSR, (2) GEMV-style transform -> y[n][512] node-major,
//           (3) CSR gather-sum + epilogue + transpose-back.
// R2: k_transform rewritten: no LDS, wave=(64 nodes, 1 bt slice), acc[64] in
//     VGPRs, W via scalar loads (uniform index -> SGPR operand in v_fma).
// ---------------------------------------------------------------------------

extern "C" __global__ void k_zero(int* __restrict__ p, int n) {
  int i = blockIdx.x * blockDim.x + threadIdx.x;
  if (i < n) p[i] = 0;
}

extern "C" __global__ void k_deg(const int* __restrict__ src, const int* __restrict__ dst,
                                 int* __restrict__ deg_out, int* __restrict__ deg_in, int E) {
  int e = blockIdx.x * blockDim.x + threadIdx.x;
  if (e < E) {
    atomicAdd(&deg_out[src[e]], 1);
    atomicAdd(&deg_in[dst[e]], 1);
  }
}

extern "C" __global__ void k_rsqrt(const int* __restrict__ dgo, const int* __restrict__ dgi,
                                   float* __restrict__ rs_out, float* __restrict__ rs_in, int N) {
  int i = blockIdx.x * blockDim.x + threadIdx.x;
  if (i < N) {
    int a = dgo[i] > 1 ? dgo[i] : 1;
    int b = dgi[i] > 1 ? dgi[i] : 1;
    rs_out[i] = rsqrtf((float)a);
    rs_in[i]  = rsqrtf((float)b);
  }
}

extern "C" __global__ __launch_bounds__(1024) void k_scan(const int* __restrict__ deg,
                                                          int* __restrict__ offs, int N) {
  __shared__ int part[1024];
  int tid = threadIdx.x;
  int chunk = (N + 1023) >> 10;
  int lo = tid * chunk;
  int hi = lo + chunk; if (hi > N) hi = N;
  int s = 0;
  for (int i = lo; i < hi; ++i) s += deg[i];
  part[tid] = s;
  __syncthreads();
  for (int off = 1; off < 1024; off <<= 1) {
    int v = part[tid];
    if (tid >= off) v += part[tid - off];
    __syncthreads();
    part[tid] = v;
    __syncthreads();
  }
  int run = (tid > 0) ? part[tid - 1] : 0;
  for (int i = lo; i < hi; ++i) { offs[i] = run; run += deg[i]; }
  if (tid == 1023) offs[N] = part[1023];
}

extern "C" __global__ void k_scatter(const int* __restrict__ src, const int* __restrict__ dst,
                                     const int* __restrict__ offs, int* __restrict__ cursor,
                                     int* __restrict__ csr_src, int E) {
  int e = blockIdx.x * blockDim.x + threadIdx.x;
  if (e < E) {
    int d = dst[e];
    int pos = offs[d] + atomicAdd(&cursor[d], 1);
    csr_src[pos] = src[e];
  }
}

// y[n][(b*4+t)*64 + f] = rs_out[n] * sum_h in_feat[((b*64+h)*4+t)*N + n] * W[h*64+f]
// wave w of block handles bt = blockIdx.y*4 + w for nodes n0..n0+63 (lane = node).
// x loads are coalesced 256B; W[h][f] is wave-uniform -> scalar loads, SGPR
// operand in the FMA. acc[64] in VGPRs. No LDS, no syncthreads.
extern "C" __global__ __launch_bounds__(256) void k_transform(
    const float* __restrict__ in_feat, const float* __restrict__ W,
    const float* __restrict__ rs_out, float* __restrict__ y, int N) {
  int tid = threadIdx.x;
  int wave = tid >> 6, lane = tid & 63;
  int bt = blockIdx.y * 4 + wave;     // 0..7
  int b = bt >> 2, t = bt & 3;
  int n = blockIdx.x * 64 + lane;

  const float* xp = in_feat + (size_t)(b * 256 + t) * (size_t)N;  // h=0 row
  size_t hstride = (size_t)4 * (size_t)N;

  float acc[64];
  #pragma unroll
  for (int f = 0; f < 64; ++f) acc[f] = 0.0f;

  bool ok = (n < N);
  #pragma unroll 4
  for (int h = 0; h < 64; ++h) {
    float xv = ok ? xp[(size_t)h * hstride + n] : 0.0f;
    const float* wrow = W + h * 64;   // wave-uniform address -> s_load
    #pragma unroll
    for (int f = 0; f < 64; ++f) acc[f] = fmaf(xv, wrow[f], acc[f]);
  }

  if (ok) {
    float rs = rs_out[n];
    float4* yp = (float4*)(y + (size_t)n * 512 + bt * 64);
    #pragma unroll
    for (int q = 0; q < 16; ++q) {
      float4 o;
      o.x = acc[q * 4 + 0] * rs;
      o.y = acc[q * 4 + 1] * rs;
      o.z = acc[q * 4 + 2] * rs;
      o.w = acc[q * 4 + 3] * rs;
      yp[q] = o;
    }
  }
}

// out[((b*64+f)*4+t)*N + n] = relu( rs_in[n] * sum_{j in CSR(n)} y[csr_src[j]][c] + bias[f] )
extern "C" __global__ __launch_bounds__(256) void k_aggregate(
    const float* __restrict__ y, const int* __restrict__ offs,
    const int* __restrict__ csr_src, const float* __restrict__ rs_in,
    const float* __restrict__ bvec, float* __restrict__ out, int N) {
  __shared__ float agg[16 * 513];  // [node][channel], pad 513 -> conflict-free epilogue
  int tid = threadIdx.x;
  int lane = tid & 63, wave = tid >> 6;
  int n0 = blockIdx.x * 16;

  #pragma unroll
  for (int k = 0; k < 4; ++k) {
    int nl = k * 4 + wave;
    int n = n0 + nl;
    float4 accA = {0.f, 0.f, 0.f, 0.f};
    float4 accB = {0.f, 0.f, 0.f, 0.f};
    if (n < N) {
      int j0 = offs[n], j1 = offs[n + 1];
      int j = j0;
      for (; j + 3 < j1; j += 4) {
        int s0 = csr_src[j], s1 = csr_src[j + 1];
        int s2 = csr_src[j + 2], s3 = csr_src[j + 3];
        const float4* r0 = (const float4*)(y + (size_t)s0 * 512);
        const float4* r1 = (const float4*)(y + (size_t)s1 * 512);
        const float4* r2 = (const float4*)(y + (size_t)s2 * 512);
        const float4* r3 = (const float4*)(y + (size_t)s3 * 512);
        float4 a0 = r0[lane], a1 = r1[lane], a2 = r2[lane], a3 = r3[lane];
        float4 b0 = r0[64 + lane], b1 = r1[64 + lane];
        float4 b2 = r2[64 + lane], b3 = r3[64 + lane];
        accA.x += (a0.x + a1.x) + (a2.x + a3.x);
        accA.y += (a0.y + a1.y) + (a2.y + a3.y);
        accA.z += (a0.z + a1.z) + (a2.z + a3.z);
        accA.w += (a0.w + a1.w) + (a2.w + a3.w);
        accB.x += (b0.x + b1.x) + (b2.x + b3.x);
        accB.y += (b0.y + b1.y) + (b2.y + b3.y);
        accB.z += (b0.z + b1.z) + (b2.z + b3.z);
        accB.w += (b0.w + b1.w) + (b2.w + b3.w);
      }
      for (; j < j1; ++j) {
        int s0 = csr_src[j];
        const float4* r0 = (const float4*)(y + (size_t)s0 * 512);
        float4 a0 = r0[lane], b0 = r0[64 + lane];
        accA.x += a0.x; accA.y += a0.y; accA.z += a0.z; accA.w += a0.w;
        accB.x += b0.x; accB.y += b0.y; accB.z += b0.z; accB.w += b0.w;
      }
    }
    *(float4*)&agg[nl * 513 + lane * 4] = accA;
    *(float4*)&agg[nl * 513 + 256 + lane * 4] = accB;
  }
  __syncthreads();

  // epilogue: scale, bias, relu, transpose-back to channel-major
  int nl = tid & 15;
  int r0 = tid >> 4;  // 0..15
  int n = n0 + nl;
  float rs = (n < N) ? rs_in[n] : 0.0f;
  #pragma unroll 4
  for (int it = 0; it < 32; ++it) {
    int c = it * 16 + r0;          // c = (b*4+t)*64 + f
    float v = agg[nl * 513 + c];
    int f = c & 63, bt = c >> 6;
    int b = bt >> 2, t = bt & 3;
    v = v * rs + bvec[f];
    v = fmaxf(v, 0.0f);
    if (n < N) out[(size_t)((b * 64 + f) * 4 + t) * (size_t)N + n] = v;
  }
}

extern "C" void kernel_launch(void* const* d_in, const int* in_sizes, int n_in,
                              void* d_out, int out_size, void* d_ws, size_t ws_size,
                              hipStream_t stream) {
  const float* in_feat = (const float*)d_in[0];
  const int*   src     = (const int*)d_in[1];
  const int*   dst     = (const int*)d_in[2];
  const float* W       = (const float*)d_in[3];
  const float* bvec    = (const float*)d_in[4];
  float* out = (float*)d_out;

  int N = in_sizes[0] / 512;   // B*H*T = 2*64*4 = 512
  int E = in_sizes[1];

  int A  = (N + 64) & ~63;     // room for N+1 offsets, 64-aligned
  int EA = (E + 63) & ~63;

  // layout: the three arrays needing zero-init come first (one contiguous memset)
  int*   deg_out_i = (int*)d_ws;        // [A]  zeroed
  int*   deg_in_i  = deg_out_i + A;     // [A]  zeroed
  int*   cursor    = deg_in_i + A;      // [A]  zeroed
  int*   offs      = cursor + A;        // [A] (N+1 used, fully written by scan)
  float* rs_out    = (float*)(offs + A);
  float* rs_in     = rs_out + A;
  int*   csr_src   = (int*)(rs_in + A); // [EA]
  float* y         = (float*)(csr_src + EA); // [N*512]

  int z = 3 * A;
  hipLaunchKernelGGL(k_zero, dim3((z + 255) / 256), dim3(256), 0, stream, deg_out_i, z);
  hipLaunchKernelGGL(k_deg, dim3((E + 255) / 256), dim3(256), 0, stream,
                     src, dst, deg_out_i, deg_in_i, E);
  hipLaunchKernelGGL(k_rsqrt, dim3((N + 255) / 256), dim3(256), 0, stream,
                     deg_out_i, deg_in_i, rs_out, rs_in, N);
  hipLaunchKernelGGL(k_scan, dim3(1), dim3(1024), 0, stream, deg_in_i, offs, N);
  hipLaunchKernelGGL(k_scatter, dim3((E + 255) / 256), dim3(256), 0, stream,
                     src, dst, offs, cursor, csr_src, E);
  hipLaunchKernelGGL(k_transform, dim3((N + 63) / 64, 2), dim3(256), 0, stream,
                     in_feat, W, rs_out, y, N);
  hipLaunchKernelGGL(k_aggregate, dim3((N + 15) / 16), dim3(256), 0, stream,
                     y, offs, csr_src, rs_in, bvec, out, N);
}

// Round 4
// 346.201 us; speedup vs baseline: 1.1795x; 1.1520x over previous
//
#include <hip/hip_runtime.h>

// ---------------------------------------------------------------------------
// GCN layer: out[b][f][t][n] = relu( rsqrt(deg_in[n]) *
//     sum_{e: dst[e]=n} ( rsqrt(deg_out[src[e]]) * x[src[e]] @ W )[b][t][f] + bias[f] )
// Strategy: (1) degrees+CSR, (2) GEMV-style transform -> y[n][512] node-major,
//           (3) CSR gather-sum + epilogue + transpose-back.
// R3: k_transform f-split: wave = 64 nodes x 1 bt x 32 f (acc[32], ~45 VGPR,
//     no AGPR spill traffic). gridDim.z=2 covers the two f halves; x is read
//     twice but second pass is L2/L3-resident and we have BW headroom.
// ---------------------------------------------------------------------------

extern "C" __global__ void k_zero(int* __restrict__ p, int n) {
  int i = blockIdx.x * blockDim.x + threadIdx.x;
  if (i < n) p[i] = 0;
}

extern "C" __global__ void k_deg(const int* __restrict__ src, const int* __restrict__ dst,
                                 int* __restrict__ deg_out, int* __restrict__ deg_in, int E) {
  int e = blockIdx.x * blockDim.x + threadIdx.x;
  if (e < E) {
    atomicAdd(&deg_out[src[e]], 1);
    atomicAdd(&deg_in[dst[e]], 1);
  }
}

extern "C" __global__ void k_rsqrt(const int* __restrict__ dgo, const int* __restrict__ dgi,
                                   float* __restrict__ rs_out, float* __restrict__ rs_in, int N) {
  int i = blockIdx.x * blockDim.x + threadIdx.x;
  if (i < N) {
    int a = dgo[i] > 1 ? dgo[i] : 1;
    int b = dgi[i] > 1 ? dgi[i] : 1;
    rs_out[i] = rsqrtf((float)a);
    rs_in[i]  = rsqrtf((float)b);
  }
}

extern "C" __global__ __launch_bounds__(1024) void k_scan(const int* __restrict__ deg,
                                                          int* __restrict__ offs, int N) {
  __shared__ int part[1024];
  int tid = threadIdx.x;
  int chunk = (N + 1023) >> 10;
  int lo = tid * chunk;
  int hi = lo + chunk; if (hi > N) hi = N;
  int s = 0;
  for (int i = lo; i < hi; ++i) s += deg[i];
  part[tid] = s;
  __syncthreads();
  for (int off = 1; off < 1024; off <<= 1) {
    int v = part[tid];
    if (tid >= off) v += part[tid - off];
    __syncthreads();
    part[tid] = v;
    __syncthreads();
  }
  int run = (tid > 0) ? part[tid - 1] : 0;
  for (int i = lo; i < hi; ++i) { offs[i] = run; run += deg[i]; }
  if (tid == 1023) offs[N] = part[1023];
}

extern "C" __global__ void k_scatter(const int* __restrict__ src, const int* __restrict__ dst,
                                     const int* __restrict__ offs, int* __restrict__ cursor,
                                     int* __restrict__ csr_src, int E) {
  int e = blockIdx.x * blockDim.x + threadIdx.x;
  if (e < E) {
    int d = dst[e];
    int pos = offs[d] + atomicAdd(&cursor[d], 1);
    csr_src[pos] = src[e];
  }
}

// y[n][(b*4+t)*64 + f] = rs_out[n] * sum_h in_feat[((b*64+h)*4+t)*N + n] * W[h*64+f]
// wave = 64 nodes (lane = node) x one bt x 32 f's. blockIdx.y picks the bt
// quad, blockIdx.z picks the f half. x loads coalesced 256B; W row uniform ->
// scalar loads feeding the FMA's SGPR operand. acc[32] in VGPRs, no LDS.
extern "C" __global__ __launch_bounds__(256) void k_transform(
    const float* __restrict__ in_feat, const float* __restrict__ W,
    const float* __restrict__ rs_out, float* __restrict__ y, int N) {
  int tid = threadIdx.x;
  int wave = tid >> 6, lane = tid & 63;
  int bt = blockIdx.y * 4 + wave;     // 0..7
  int b = bt >> 2, t = bt & 3;
  int fh = blockIdx.z * 32;           // f half: 0 or 32
  int n = blockIdx.x * 64 + lane;

  const float* xp = in_feat + (size_t)(b * 256 + t) * (size_t)N;  // h=0 row
  size_t hstride = (size_t)4 * (size_t)N;

  float acc[32];
  #pragma unroll
  for (int f = 0; f < 32; ++f) acc[f] = 0.0f;

  bool ok = (n < N);
  #pragma unroll 4
  for (int h = 0; h < 64; ++h) {
    float xv = ok ? xp[(size_t)h * hstride + n] : 0.0f;
    const float* wrow = W + h * 64 + fh;   // wave-uniform address -> s_load
    #pragma unroll
    for (int f = 0; f < 32; ++f) acc[f] = fmaf(xv, wrow[f], acc[f]);
  }

  if (ok) {
    float rs = rs_out[n];
    float4* yp = (float4*)(y + (size_t)n * 512 + bt * 64 + fh);
    #pragma unroll
    for (int q = 0; q < 8; ++q) {
      float4 o;
      o.x = acc[q * 4 + 0] * rs;
      o.y = acc[q * 4 + 1] * rs;
      o.z = acc[q * 4 + 2] * rs;
      o.w = acc[q * 4 + 3] * rs;
      yp[q] = o;
    }
  }
}

// out[((b*64+f)*4+t)*N + n] = relu( rs_in[n] * sum_{j in CSR(n)} y[csr_src[j]][c] + bias[f] )
extern "C" __global__ __launch_bounds__(256) void k_aggregate(
    const float* __restrict__ y, const int* __restrict__ offs,
    const int* __restrict__ csr_src, const float* __restrict__ rs_in,
    const float* __restrict__ bvec, float* __restrict__ out, int N) {
  __shared__ float agg[16 * 513];  // [node][channel], pad 513 -> conflict-free epilogue
  int tid = threadIdx.x;
  int lane = tid & 63, wave = tid >> 6;
  int n0 = blockIdx.x * 16;

  #pragma unroll
  for (int k = 0; k < 4; ++k) {
    int nl = k * 4 + wave;
    int n = n0 + nl;
    float4 accA = {0.f, 0.f, 0.f, 0.f};
    float4 accB = {0.f, 0.f, 0.f, 0.f};
    if (n < N) {
      int j0 = offs[n], j1 = offs[n + 1];
      int j = j0;
      for (; j + 3 < j1; j += 4) {
        int s0 = csr_src[j], s1 = csr_src[j + 1];
        int s2 = csr_src[j + 2], s3 = csr_src[j + 3];
        const float4* r0 = (const float4*)(y + (size_t)s0 * 512);
        const float4* r1 = (const float4*)(y + (size_t)s1 * 512);
        const float4* r2 = (const float4*)(y + (size_t)s2 * 512);
        const float4* r3 = (const float4*)(y + (size_t)s3 * 512);
        float4 a0 = r0[lane], a1 = r1[lane], a2 = r2[lane], a3 = r3[lane];
        float4 b0 = r0[64 + lane], b1 = r1[64 + lane];
        float4 b2 = r2[64 + lane], b3 = r3[64 + lane];
        accA.x += (a0.x + a1.x) + (a2.x + a3.x);
        accA.y += (a0.y + a1.y) + (a2.y + a3.y);
        accA.z += (a0.z + a1.z) + (a2.z + a3.z);
        accA.w += (a0.w + a1.w) + (a2.w + a3.w);
        accB.x += (b0.x + b1.x) + (b2.x + b3.x);
        accB.y += (b0.y + b1.y) + (b2.y + b3.y);
        accB.z += (b0.z + b1.z) + (b2.z + b3.z);
        accB.w += (b0.w + b1.w) + (b2.w + b3.w);
      }
      for (; j < j1; ++j) {
        int s0 = csr_src[j];
        const float4* r0 = (const float4*)(y + (size_t)s0 * 512);
        float4 a0 = r0[lane], b0 = r0[64 + lane];
        accA.x += a0.x; accA.y += a0.y; accA.z += a0.z; accA.w += a0.w;
        accB.x += b0.x; accB.y += b0.y; accB.z += b0.z; accB.w += b0.w;
      }
    }
    *(float4*)&agg[nl * 513 + lane * 4] = accA;
    *(float4*)&agg[nl * 513 + 256 + lane * 4] = accB;
  }
  __syncthreads();

  // epilogue: scale, bias, relu, transpose-back to channel-major
  int nl = tid & 15;
  int r0 = tid >> 4;  // 0..15
  int n = n0 + nl;
  float rs = (n < N) ? rs_in[n] : 0.0f;
  #pragma unroll 4
  for (int it = 0; it < 32; ++it) {
    int c = it * 16 + r0;          // c = (b*4+t)*64 + f
    float v = agg[nl * 513 + c];
    int f = c & 63, bt = c >> 6;
    int b = bt >> 2, t = bt & 3;
    v = v * rs + bvec[f];
    v = fmaxf(v, 0.0f);
    if (n < N) out[(size_t)((b * 64 + f) * 4 + t) * (size_t)N + n] = v;
  }
}

extern "C" void kernel_launch(void* const* d_in, const int* in_sizes, int n_in,
                              void* d_out, int out_size, void* d_ws, size_t ws_size,
                              hipStream_t stream) {
  const float* in_feat = (const float*)d_in[0];
  const int*   src     = (const int*)d_in[1];
  const int*   dst     = (const int*)d_in[2];
  const float* W       = (const float*)d_in[3];
  const float* bvec    = (const float*)d_in[4];
  float* out = (float*)d_out;

  int N = in_sizes[0] / 512;   // B*H*T = 2*64*4 = 512
  int E = in_sizes[1];

  int A  = (N + 64) & ~63;     // room for N+1 offsets, 64-aligned
  int EA = (E + 63) & ~63;

  // layout: the three arrays needing zero-init come first (one contiguous memset)
  int*   deg_out_i = (int*)d_ws;        // [A]  zeroed
  int*   deg_in_i  = deg_out_i + A;     // [A]  zeroed
  int*   cursor    = deg_in_i + A;      // [A]  zeroed
  int*   offs      = cursor + A;        // [A] (N+1 used, fully written by scan)
  float* rs_out    = (float*)(offs + A);
  float* rs_in     = rs_out + A;
  int*   csr_src   = (int*)(rs_in + A); // [EA]
  float* y         = (float*)(csr_src + EA); // [N*512]

  int z = 3 * A;
  hipLaunchKernelGGL(k_zero, dim3((z + 255) / 256), dim3(256), 0, stream, deg_out_i, z);
  hipLaunchKernelGGL(k_deg, dim3((E + 255) / 256), dim3(256), 0, stream,
                     src, dst, deg_out_i, deg_in_i, E);
  hipLaunchKernelGGL(k_rsqrt, dim3((N + 255) / 256), dim3(256), 0, stream,
                     deg_out_i, deg_in_i, rs_out, rs_in, N);
  hipLaunchKernelGGL(k_scan, dim3(1), dim3(1024), 0, stream, deg_in_i, offs, N);
  hipLaunchKernelGGL(k_scatter, dim3((E + 255) / 256), dim3(256), 0, stream,
                     src, dst, offs, cursor, csr_src, E);
  hipLaunchKernelGGL(k_transform, dim3((N + 63) / 64, 2, 2), dim3(256), 0, stream,
                     in_feat, W, rs_out, y, N);
  hipLaunchKernelGGL(k_aggregate, dim3((N + 15) / 16), dim3(256), 0, stream,
                     y, offs, csr_src, rs_in, bvec, out, N);
}

// Round 5
// 272.995 us; speedup vs baseline: 1.4958x; 1.2682x over previous
//
#include <hip/hip_runtime.h>
#include <hip/hip_fp16.h>

// ---------------------------------------------------------------------------
// GCN layer: out[b][f][t][n] = relu( rsqrt(deg_in[n]) *
//     sum_{e: dst[e]=n} ( rsqrt(deg_out[src[e]]) * x[src[e]] @ W )[b][t][f] + bias[f] )
// Strategy: (1) degrees+CSR, (2) GEMV-style transform -> y[n][512] fp16
//           node-major, (3) CSR gather-sum + epilogue + transpose-back.
// R4: y stored fp16 (halves gather bytes; |y|~N(0,1), fp16 err ~1e-2 << 4.4e-2
//     threshold). Aggregate: one coalesced lane-parallel CSR index load per
//     node + readlane broadcast -> per-edge chain is readlane + 2 independent
//     8B loads (no serialized index fetches).
// ---------------------------------------------------------------------------

extern "C" __global__ void k_zero(int* __restrict__ p, int n) {
  int i = blockIdx.x * blockDim.x + threadIdx.x;
  if (i < n) p[i] = 0;
}

extern "C" __global__ void k_deg(const int* __restrict__ src, const int* __restrict__ dst,
                                 int* __restrict__ deg_out, int* __restrict__ deg_in, int E) {
  int e = blockIdx.x * blockDim.x + threadIdx.x;
  if (e < E) {
    atomicAdd(&deg_out[src[e]], 1);
    atomicAdd(&deg_in[dst[e]], 1);
  }
}

extern "C" __global__ void k_rsqrt(const int* __restrict__ dgo, const int* __restrict__ dgi,
                                   float* __restrict__ rs_out, float* __restrict__ rs_in, int N) {
  int i = blockIdx.x * blockDim.x + threadIdx.x;
  if (i < N) {
    int a = dgo[i] > 1 ? dgo[i] : 1;
    int b = dgi[i] > 1 ? dgi[i] : 1;
    rs_out[i] = rsqrtf((float)a);
    rs_in[i]  = rsqrtf((float)b);
  }
}

extern "C" __global__ __launch_bounds__(1024) void k_scan(const int* __restrict__ deg,
                                                          int* __restrict__ offs, int N) {
  __shared__ int part[1024];
  int tid = threadIdx.x;
  int chunk = (N + 1023) >> 10;
  int lo = tid * chunk;
  int hi = lo + chunk; if (hi > N) hi = N;
  int s = 0;
  for (int i = lo; i < hi; ++i) s += deg[i];
  part[tid] = s;
  __syncthreads();
  for (int off = 1; off < 1024; off <<= 1) {
    int v = part[tid];
    if (tid >= off) v += part[tid - off];
    __syncthreads();
    part[tid] = v;
    __syncthreads();
  }
  int run = (tid > 0) ? part[tid - 1] : 0;
  for (int i = lo; i < hi; ++i) { offs[i] = run; run += deg[i]; }
  if (tid == 1023) offs[N] = part[1023];
}

extern "C" __global__ void k_scatter(const int* __restrict__ src, const int* __restrict__ dst,
                                     const int* __restrict__ offs, int* __restrict__ cursor,
                                     int* __restrict__ csr_src, int E) {
  int e = blockIdx.x * blockDim.x + threadIdx.x;
  if (e < E) {
    int d = dst[e];
    int pos = offs[d] + atomicAdd(&cursor[d], 1);
    csr_src[pos] = src[e];
  }
}

// y[n][(b*4+t)*64 + f] (fp16) = rs_out[n] * sum_h x[((b*64+h)*4+t)*N + n] * W[h*64+f]
// wave = 64 nodes (lane = node) x one bt x 32 f's. blockIdx.y picks the bt
// quad, blockIdx.z picks the f half. acc[32] fp32 in VGPRs; W via scalar loads.
extern "C" __global__ __launch_bounds__(256) void k_transform(
    const float* __restrict__ in_feat, const float* __restrict__ W,
    const float* __restrict__ rs_out, __half* __restrict__ y, int N) {
  int tid = threadIdx.x;
  int wave = tid >> 6, lane = tid & 63;
  int bt = blockIdx.y * 4 + wave;     // 0..7
  int b = bt >> 2, t = bt & 3;
  int fh = blockIdx.z * 32;           // f half: 0 or 32
  int n = blockIdx.x * 64 + lane;

  const float* xp = in_feat + (size_t)(b * 256 + t) * (size_t)N;  // h=0 row
  size_t hstride = (size_t)4 * (size_t)N;

  float acc[32];
  #pragma unroll
  for (int f = 0; f < 32; ++f) acc[f] = 0.0f;

  bool ok = (n < N);
  #pragma unroll 4
  for (int h = 0; h < 64; ++h) {
    float xv = ok ? xp[(size_t)h * hstride + n] : 0.0f;
    const float* wrow = W + h * 64 + fh;   // wave-uniform address -> s_load
    #pragma unroll
    for (int f = 0; f < 32; ++f) acc[f] = fmaf(xv, wrow[f], acc[f]);
  }

  if (ok) {
    float rs = rs_out[n];
    union { unsigned int u[16]; uint4 v[4]; } pk;
    #pragma unroll
    for (int q = 0; q < 16; ++q) {
      __half2 h = __float22half2_rn(make_float2(acc[2 * q] * rs, acc[2 * q + 1] * rs));
      pk.u[q] = *(unsigned int*)&h;
    }
    uint4* yp = (uint4*)(y + (size_t)n * 512 + bt * 64 + fh);
    #pragma unroll
    for (int q = 0; q < 4; ++q) yp[q] = pk.v[q];
  }
}

// out[((b*64+f)*4+t)*N + n] = relu( rs_in[n] * sum_{j in CSR(n)} y[csr_src[j]][c] + bias[f] )
// wave per node: lane-parallel CSR index block load, readlane broadcast,
// per-edge 2x8B independent loads. accA = channels [4*lane,4*lane+4),
// accB = [256+4*lane, ...). LDS epilogue transposes to channel-major.
extern "C" __global__ __launch_bounds__(256) void k_aggregate(
    const __half* __restrict__ y, const int* __restrict__ offs,
    const int* __restrict__ csr_src, const float* __restrict__ rs_in,
    const float* __restrict__ bvec, float* __restrict__ out, int N) {
  __shared__ float agg[16 * 513];  // [node][channel], pad 513 -> conflict-free epilogue
  int tid = threadIdx.x;
  int lane = tid & 63, wave = tid >> 6;
  int n0 = blockIdx.x * 16;

#define ACC_EDGE(s)                                                          \
  {                                                                          \
    const uint2* rp = (const uint2*)(y + (size_t)(s) * 512);                 \
    uint2 ua = rp[lane];                                                     \
    uint2 ub = rp[64 + lane];                                                \
    float2 f;                                                                \
    f = __half22float2(*(const __half2*)&ua.x); accA.x += f.x; accA.y += f.y;\
    f = __half22float2(*(const __half2*)&ua.y); accA.z += f.x; accA.w += f.y;\
    f = __half22float2(*(const __half2*)&ub.x); accB.x += f.x; accB.y += f.y;\
    f = __half22float2(*(const __half2*)&ub.y); accB.z += f.x; accB.w += f.y;\
  }

  #pragma unroll
  for (int k = 0; k < 4; ++k) {
    int nl = k * 4 + wave;
    int n = n0 + nl;
    float4 accA = {0.f, 0.f, 0.f, 0.f};
    float4 accB = {0.f, 0.f, 0.f, 0.f};
    if (n < N) {
      int j0 = offs[n], j1 = offs[n + 1];
      for (int base = j0; base < j1; base += 64) {
        int idxv = csr_src[base + lane];  // coalesced block of up to 64 indices
        int m = j1 - base; if (m > 64) m = 64;
        int e = 0;
        for (; e + 3 < m; e += 4) {
          int s0 = __builtin_amdgcn_readlane(idxv, e);
          int s1 = __builtin_amdgcn_readlane(idxv, e + 1);
          int s2 = __builtin_amdgcn_readlane(idxv, e + 2);
          int s3 = __builtin_amdgcn_readlane(idxv, e + 3);
          ACC_EDGE(s0); ACC_EDGE(s1); ACC_EDGE(s2); ACC_EDGE(s3);
        }
        for (; e < m; ++e) {
          int s0 = __builtin_amdgcn_readlane(idxv, e);
          ACC_EDGE(s0);
        }
      }
    }
    *(float4*)&agg[nl * 513 + lane * 4] = accA;
    *(float4*)&agg[nl * 513 + 256 + lane * 4] = accB;
  }
#undef ACC_EDGE
  __syncthreads();

  // epilogue: scale, bias, relu, transpose-back to channel-major
  int nl = tid & 15;
  int r0 = tid >> 4;  // 0..15
  int n = n0 + nl;
  float rs = (n < N) ? rs_in[n] : 0.0f;
  #pragma unroll 4
  for (int it = 0; it < 32; ++it) {
    int c = it * 16 + r0;          // c = (b*4+t)*64 + f
    float v = agg[nl * 513 + c];
    int f = c & 63, bt = c >> 6;
    int b = bt >> 2, t = bt & 3;
    v = v * rs + bvec[f];
    v = fmaxf(v, 0.0f);
    if (n < N) out[(size_t)((b * 64 + f) * 4 + t) * (size_t)N + n] = v;
  }
}

extern "C" void kernel_launch(void* const* d_in, const int* in_sizes, int n_in,
                              void* d_out, int out_size, void* d_ws, size_t ws_size,
                              hipStream_t stream) {
  const float* in_feat = (const float*)d_in[0];
  const int*   src     = (const int*)d_in[1];
  const int*   dst     = (const int*)d_in[2];
  const float* W       = (const float*)d_in[3];
  const float* bvec    = (const float*)d_in[4];
  float* out = (float*)d_out;

  int N = in_sizes[0] / 512;   // B*H*T = 2*64*4 = 512
  int E = in_sizes[1];

  int A  = (N + 64) & ~63;     // room for N+1 offsets, 64-aligned
  int EA = (E + 63) & ~63;

  // layout: the three arrays needing zero-init come first (one contiguous memset)
  int*   deg_out_i = (int*)d_ws;        // [A]  zeroed
  int*   deg_in_i  = deg_out_i + A;     // [A]  zeroed
  int*   cursor    = deg_in_i + A;      // [A]  zeroed
  int*   offs      = cursor + A;        // [A] (N+1 used, fully written by scan)
  float* rs_out    = (float*)(offs + A);
  float* rs_in     = rs_out + A;
  int*   csr_src   = (int*)(rs_in + A); // [EA] (+64 slack: y follows, overreads safe)
  __half* y        = (__half*)(csr_src + EA); // [N*512] fp16

  int z = 3 * A;
  hipLaunchKernelGGL(k_zero, dim3((z + 255) / 256), dim3(256), 0, stream, deg_out_i, z);
  hipLaunchKernelGGL(k_deg, dim3((E + 255) / 256), dim3(256), 0, stream,
                     src, dst, deg_out_i, deg_in_i, E);
  hipLaunchKernelGGL(k_rsqrt, dim3((N + 255) / 256), dim3(256), 0, stream,
                     deg_out_i, deg_in_i, rs_out, rs_in, N);
  hipLaunchKernelGGL(k_scan, dim3(1), dim3(1024), 0, stream, deg_in_i, offs, N);
  hipLaunchKernelGGL(k_scatter, dim3((E + 255) / 256), dim3(256), 0, stream,
                     src, dst, offs, cursor, csr_src, E);
  hipLaunchKernelGGL(k_transform, dim3((N + 63) / 64, 2, 2), dim3(256), 0, stream,
                     in_feat, W, rs_out, y, N);
  hipLaunchKernelGGL(k_aggregate, dim3((N + 15) / 16), dim3(256), 0, stream,
                     y, offs, csr_src, rs_in, bvec, out, N);
}

// Round 6
// 250.997 us; speedup vs baseline: 1.6269x; 1.0876x over previous
//
#include <hip/hip_runtime.h>
#include <hip/hip_fp16.h>

// ---------------------------------------------------------------------------
// GCN layer: out[b][f][t][n] = relu( rsqrt(deg_in[n]) *
//     sum_{e: dst[e]=n} ( rsqrt(deg_out[src[e]]) * x[src[e]] @ W )[b][t][f] + bias[f] )
// Strategy: (1) degrees+CSR, (2) GEMV-style transform -> y[n][512] fp16
//           node-major, (3) CSR gather-sum + epilogue + transpose-back.
// R5: single-block k_scan (uncoalesced, 1 CU, ~50+us) replaced by 3-phase
//     multi-block scan (coalesced, ~4us). Transform h-loop unroll 4->8.
// ---------------------------------------------------------------------------

extern "C" __global__ void k_zero(int* __restrict__ p, int n) {
  int i = blockIdx.x * blockDim.x + threadIdx.x;
  if (i < n) p[i] = 0;
}

extern "C" __global__ void k_deg(const int* __restrict__ src, const int* __restrict__ dst,
                                 int* __restrict__ deg_out, int* __restrict__ deg_in, int E) {
  int e = blockIdx.x * blockDim.x + threadIdx.x;
  if (e < E) {
    atomicAdd(&deg_out[src[e]], 1);
    atomicAdd(&deg_in[dst[e]], 1);
  }
}

extern "C" __global__ void k_rsqrt(const int* __restrict__ dgo, const int* __restrict__ dgi,
                                   float* __restrict__ rs_out, float* __restrict__ rs_in, int N) {
  int i = blockIdx.x * blockDim.x + threadIdx.x;
  if (i < N) {
    int a = dgo[i] > 1 ? dgo[i] : 1;
    int b = dgi[i] > 1 ? dgi[i] : 1;
    rs_out[i] = rsqrtf((float)a);
    rs_in[i]  = rsqrtf((float)b);
  }
}

// --- 3-phase exclusive scan of deg_in -> offs (N <= 65536: block sums <= 256)
extern "C" __global__ __launch_bounds__(256) void k_scan1(const int* __restrict__ deg,
                                                          int* __restrict__ bsum, int N) {
  __shared__ int red[256];
  int tid = threadIdx.x;
  int i = blockIdx.x * 256 + tid;
  red[tid] = (i < N) ? deg[i] : 0;
  __syncthreads();
  #pragma unroll
  for (int off = 128; off > 0; off >>= 1) {
    if (tid < off) red[tid] += red[tid + off];
    __syncthreads();
  }
  if (tid == 0) bsum[blockIdx.x] = red[0];
}

extern "C" __global__ __launch_bounds__(256) void k_scan2(const int* __restrict__ bsum,
                                                          int* __restrict__ boffs,
                                                          int* __restrict__ offs, int M, int N) {
  __shared__ int sc[256];
  int tid = threadIdx.x;
  int v = (tid < M) ? bsum[tid] : 0;
  sc[tid] = v;
  __syncthreads();
  #pragma unroll
  for (int off = 1; off < 256; off <<= 1) {
    int t = sc[tid];
    if (tid >= off) t += sc[tid - off];
    __syncthreads();
    sc[tid] = t;
    __syncthreads();
  }
  boffs[tid] = sc[tid] - v;           // exclusive block offset
  if (tid == 255) offs[N] = sc[255];  // total edge count
}

extern "C" __global__ __launch_bounds__(256) void k_scan3(const int* __restrict__ deg,
                                                          const int* __restrict__ boffs,
                                                          int* __restrict__ offs, int N) {
  __shared__ int sc[256];
  int tid = threadIdx.x;
  int i = blockIdx.x * 256 + tid;
  int v = (i < N) ? deg[i] : 0;
  sc[tid] = v;
  __syncthreads();
  #pragma unroll
  for (int off = 1; off < 256; off <<= 1) {
    int t = sc[tid];
    if (tid >= off) t += sc[tid - off];
    __syncthreads();
    sc[tid] = t;
    __syncthreads();
  }
  if (i < N) offs[i] = boffs[blockIdx.x] + sc[tid] - v;
}

extern "C" __global__ void k_scatter(const int* __restrict__ src, const int* __restrict__ dst,
                                     const int* __restrict__ offs, int* __restrict__ cursor,
                                     int* __restrict__ csr_src, int E) {
  int e = blockIdx.x * blockDim.x + threadIdx.x;
  if (e < E) {
    int d = dst[e];
    int pos = offs[d] + atomicAdd(&cursor[d], 1);
    csr_src[pos] = src[e];
  }
}

// y[n][(b*4+t)*64 + f] (fp16) = rs_out[n] * sum_h x[((b*64+h)*4+t)*N + n] * W[h*64+f]
// wave = 64 nodes (lane = node) x one bt x 32 f's. blockIdx.y picks the bt
// quad, blockIdx.z picks the f half. acc[32] fp32 in VGPRs; W via scalar loads.
extern "C" __global__ __launch_bounds__(256) void k_transform(
    const float* __restrict__ in_feat, const float* __restrict__ W,
    const float* __restrict__ rs_out, __half* __restrict__ y, int N) {
  int tid = threadIdx.x;
  int wave = tid >> 6, lane = tid & 63;
  int bt = blockIdx.y * 4 + wave;     // 0..7
  int b = bt >> 2, t = bt & 3;
  int fh = blockIdx.z * 32;           // f half: 0 or 32
  int n = blockIdx.x * 64 + lane;

  const float* xp = in_feat + (size_t)(b * 256 + t) * (size_t)N;  // h=0 row
  size_t hstride = (size_t)4 * (size_t)N;

  float acc[32];
  #pragma unroll
  for (int f = 0; f < 32; ++f) acc[f] = 0.0f;

  bool ok = (n < N);
  #pragma unroll 8
  for (int h = 0; h < 64; ++h) {
    float xv = ok ? xp[(size_t)h * hstride + n] : 0.0f;
    const float* wrow = W + h * 64 + fh;   // wave-uniform address -> s_load
    #pragma unroll
    for (int f = 0; f < 32; ++f) acc[f] = fmaf(xv, wrow[f], acc[f]);
  }

  if (ok) {
    float rs = rs_out[n];
    union { unsigned int u[16]; uint4 v[4]; } pk;
    #pragma unroll
    for (int q = 0; q < 16; ++q) {
      __half2 h = __float22half2_rn(make_float2(acc[2 * q] * rs, acc[2 * q + 1] * rs));
      pk.u[q] = *(unsigned int*)&h;
    }
    uint4* yp = (uint4*)(y + (size_t)n * 512 + bt * 64 + fh);
    #pragma unroll
    for (int q = 0; q < 4; ++q) yp[q] = pk.v[q];
  }
}

// out[((b*64+f)*4+t)*N + n] = relu( rs_in[n] * sum_{j in CSR(n)} y[csr_src[j]][c] + bias[f] )
// wave per node: lane-parallel CSR index block load, readlane broadcast,
// per-edge 2x8B independent loads. accA = channels [4*lane,4*lane+4),
// accB = [256+4*lane, ...). LDS epilogue transposes to channel-major.
extern "C" __global__ __launch_bounds__(256) void k_aggregate(
    const __half* __restrict__ y, const int* __restrict__ offs,
    const int* __restrict__ csr_src, const float* __restrict__ rs_in,
    const float* __restrict__ bvec, float* __restrict__ out, int N) {
  __shared__ float agg[16 * 513];  // [node][channel], pad 513 -> conflict-free epilogue
  int tid = threadIdx.x;
  int lane = tid & 63, wave = tid >> 6;
  int n0 = blockIdx.x * 16;

#define ACC_EDGE(s)                                                          \
  {                                                                          \
    const uint2* rp = (const uint2*)(y + (size_t)(s) * 512);                 \
    uint2 ua = rp[lane];                                                     \
    uint2 ub = rp[64 + lane];                                                \
    float2 f;                                                                \
    f = __half22float2(*(const __half2*)&ua.x); accA.x += f.x; accA.y += f.y;\
    f = __half22float2(*(const __half2*)&ua.y); accA.z += f.x; accA.w += f.y;\
    f = __half22float2(*(const __half2*)&ub.x); accB.x += f.x; accB.y += f.y;\
    f = __half22float2(*(const __half2*)&ub.y); accB.z += f.x; accB.w += f.y;\
  }

  #pragma unroll
  for (int k = 0; k < 4; ++k) {
    int nl = k * 4 + wave;
    int n = n0 + nl;
    float4 accA = {0.f, 0.f, 0.f, 0.f};
    float4 accB = {0.f, 0.f, 0.f, 0.f};
    if (n < N) {
      int j0 = offs[n], j1 = offs[n + 1];
      for (int base = j0; base < j1; base += 64) {
        int idxv = csr_src[base + lane];  // coalesced block of up to 64 indices
        int m = j1 - base; if (m > 64) m = 64;
        int e = 0;
        for (; e + 3 < m; e += 4) {
          int s0 = __builtin_amdgcn_readlane(idxv, e);
          int s1 = __builtin_amdgcn_readlane(idxv, e + 1);
          int s2 = __builtin_amdgcn_readlane(idxv, e + 2);
          int s3 = __builtin_amdgcn_readlane(idxv, e + 3);
          ACC_EDGE(s0); ACC_EDGE(s1); ACC_EDGE(s2); ACC_EDGE(s3);
        }
        for (; e < m; ++e) {
          int s0 = __builtin_amdgcn_readlane(idxv, e);
          ACC_EDGE(s0);
        }
      }
    }
    *(float4*)&agg[nl * 513 + lane * 4] = accA;
    *(float4*)&agg[nl * 513 + 256 + lane * 4] = accB;
  }
#undef ACC_EDGE
  __syncthreads();

  // epilogue: scale, bias, relu, transpose-back to channel-major
  int nl = tid & 15;
  int r0 = tid >> 4;  // 0..15
  int n = n0 + nl;
  float rs = (n < N) ? rs_in[n] : 0.0f;
  #pragma unroll 4
  for (int it = 0; it < 32; ++it) {
    int c = it * 16 + r0;          // c = (b*4+t)*64 + f
    float v = agg[nl * 513 + c];
    int f = c & 63, bt = c >> 6;
    int b = bt >> 2, t = bt & 3;
    v = v * rs + bvec[f];
    v = fmaxf(v, 0.0f);
    if (n < N) out[(size_t)((b * 64 + f) * 4 + t) * (size_t)N + n] = v;
  }
}

extern "C" void kernel_launch(void* const* d_in, const int* in_sizes, int n_in,
                              void* d_out, int out_size, void* d_ws, size_t ws_size,
                              hipStream_t stream) {
  const float* in_feat = (const float*)d_in[0];
  const int*   src     = (const int*)d_in[1];
  const int*   dst     = (const int*)d_in[2];
  const float* W       = (const float*)d_in[3];
  const float* bvec    = (const float*)d_in[4];
  float* out = (float*)d_out;

  int N = in_sizes[0] / 512;   // B*H*T = 2*64*4 = 512
  int E = in_sizes[1];

  int A  = (N + 64) & ~63;     // room for N+1 offsets, 64-aligned
  int EA = (E + 63) & ~63;
  int M  = (N + 255) / 256;    // scan blocks (<= 256 for N <= 65536)

  // layout: the three arrays needing zero-init come first (one contiguous memset)
  int*   deg_out_i = (int*)d_ws;        // [A]  zeroed
  int*   deg_in_i  = deg_out_i + A;     // [A]  zeroed
  int*   cursor    = deg_in_i + A;      // [A]  zeroed
  int*   offs      = cursor + A;        // [A] (N+1 used, fully written by scans)
  int*   bsum      = offs + A;          // [256]
  int*   boffs     = bsum + 256;        // [256]
  float* rs_out    = (float*)(boffs + 256);
  float* rs_in     = rs_out + A;
  int*   csr_src   = (int*)(rs_in + A); // [EA] (+slack: y follows, overreads safe)
  __half* y        = (__half*)(csr_src + EA); // [N*512] fp16

  int z = 3 * A;
  hipLaunchKernelGGL(k_zero, dim3((z + 255) / 256), dim3(256), 0, stream, deg_out_i, z);
  hipLaunchKernelGGL(k_deg, dim3((E + 255) / 256), dim3(256), 0, stream,
                     src, dst, deg_out_i, deg_in_i, E);
  hipLaunchKernelGGL(k_rsqrt, dim3((N + 255) / 256), dim3(256), 0, stream,
                     deg_out_i, deg_in_i, rs_out, rs_in, N);
  hipLaunchKernelGGL(k_scan1, dim3(M), dim3(256), 0, stream, deg_in_i, bsum, N);
  hipLaunchKernelGGL(k_scan2, dim3(1), dim3(256), 0, stream, bsum, boffs, offs, M, N);
  hipLaunchKernelGGL(k_scan3, dim3(M), dim3(256), 0, stream, deg_in_i, boffs, offs, N);
  hipLaunchKernelGGL(k_scatter, dim3((E + 255) / 256), dim3(256), 0, stream,
                     src, dst, offs, cursor, csr_src, E);
  hipLaunchKernelGGL(k_transform, dim3((N + 63) / 64, 2, 2), dim3(256), 0, stream,
                     in_feat, W, rs_out, y, N);
  hipLaunchKernelGGL(k_aggregate, dim3((N + 15) / 16), dim3(256), 0, stream,
                     y, offs, csr_src, rs_in, bvec, out, N);
}

// Round 7
// 200.867 us; speedup vs baseline: 2.0329x; 1.2496x over previous
//
#include <hip/hip_runtime.h>
#include <hip/hip_fp16.h>

// ---------------------------------------------------------------------------
// GCN layer: out[b][f][t][n] = relu( rsqrt(deg_in[n]) *
//     sum_{e: dst[e]=n} ( rsqrt(deg_out[src[e]]) * x[src[e]] @ W )[b][t][f] + bias[f] )
// Strategy: (1) degrees+CSR, (2) GEMV-style transform -> y[n][512] fp16
//           node-major, (3) CSR gather-sum + epilogue + transpose-back.
// R6: transform reverted to unroll 4 (unroll 8 blew the reg budget: VALUBusy
//     37->65% same FETCH, +43us). Aggregate: 512-thread blocks (8 waves) on
//     the same 16-node/33KB tile -> 4 blocks/CU = 32 waves/CU (100% cap).
// ---------------------------------------------------------------------------

extern "C" __global__ void k_zero(int* __restrict__ p, int n) {
  int i = blockIdx.x * blockDim.x + threadIdx.x;
  if (i < n) p[i] = 0;
}

extern "C" __global__ void k_deg(const int* __restrict__ src, const int* __restrict__ dst,
                                 int* __restrict__ deg_out, int* __restrict__ deg_in, int E) {
  int e = blockIdx.x * blockDim.x + threadIdx.x;
  if (e < E) {
    atomicAdd(&deg_out[src[e]], 1);
    atomicAdd(&deg_in[dst[e]], 1);
  }
}

extern "C" __global__ void k_rsqrt(const int* __restrict__ dgo, const int* __restrict__ dgi,
                                   float* __restrict__ rs_out, float* __restrict__ rs_in, int N) {
  int i = blockIdx.x * blockDim.x + threadIdx.x;
  if (i < N) {
    int a = dgo[i] > 1 ? dgo[i] : 1;
    int b = dgi[i] > 1 ? dgi[i] : 1;
    rs_out[i] = rsqrtf((float)a);
    rs_in[i]  = rsqrtf((float)b);
  }
}

// --- 3-phase exclusive scan of deg_in -> offs (N <= 65536: block sums <= 256)
extern "C" __global__ __launch_bounds__(256) void k_scan1(const int* __restrict__ deg,
                                                          int* __restrict__ bsum, int N) {
  __shared__ int red[256];
  int tid = threadIdx.x;
  int i = blockIdx.x * 256 + tid;
  red[tid] = (i < N) ? deg[i] : 0;
  __syncthreads();
  #pragma unroll
  for (int off = 128; off > 0; off >>= 1) {
    if (tid < off) red[tid] += red[tid + off];
    __syncthreads();
  }
  if (tid == 0) bsum[blockIdx.x] = red[0];
}

extern "C" __global__ __launch_bounds__(256) void k_scan2(const int* __restrict__ bsum,
                                                          int* __restrict__ boffs,
                                                          int* __restrict__ offs, int M, int N) {
  __shared__ int sc[256];
  int tid = threadIdx.x;
  int v = (tid < M) ? bsum[tid] : 0;
  sc[tid] = v;
  __syncthreads();
  #pragma unroll
  for (int off = 1; off < 256; off <<= 1) {
    int t = sc[tid];
    if (tid >= off) t += sc[tid - off];
    __syncthreads();
    sc[tid] = t;
    __syncthreads();
  }
  boffs[tid] = sc[tid] - v;           // exclusive block offset
  if (tid == 255) offs[N] = sc[255];  // total edge count
}

extern "C" __global__ __launch_bounds__(256) void k_scan3(const int* __restrict__ deg,
                                                          const int* __restrict__ boffs,
                                                          int* __restrict__ offs, int N) {
  __shared__ int sc[256];
  int tid = threadIdx.x;
  int i = blockIdx.x * 256 + tid;
  int v = (i < N) ? deg[i] : 0;
  sc[tid] = v;
  __syncthreads();
  #pragma unroll
  for (int off = 1; off < 256; off <<= 1) {
    int t = sc[tid];
    if (tid >= off) t += sc[tid - off];
    __syncthreads();
    sc[tid] = t;
    __syncthreads();
  }
  if (i < N) offs[i] = boffs[blockIdx.x] + sc[tid] - v;
}

extern "C" __global__ void k_scatter(const int* __restrict__ src, const int* __restrict__ dst,
                                     const int* __restrict__ offs, int* __restrict__ cursor,
                                     int* __restrict__ csr_src, int E) {
  int e = blockIdx.x * blockDim.x + threadIdx.x;
  if (e < E) {
    int d = dst[e];
    int pos = offs[d] + atomicAdd(&cursor[d], 1);
    csr_src[pos] = src[e];
  }
}

// y[n][(b*4+t)*64 + f] (fp16) = rs_out[n] * sum_h x[((b*64+h)*4+t)*N + n] * W[h*64+f]
// wave = 64 nodes (lane = node) x one bt x 32 f's. blockIdx.y picks the bt
// quad, blockIdx.z picks the f half. acc[32] fp32 in VGPRs; W via scalar loads.
// NOTE: h-loop unroll stays at 4 — unroll 8 overflows the reg budget (R6).
extern "C" __global__ __launch_bounds__(256) void k_transform(
    const float* __restrict__ in_feat, const float* __restrict__ W,
    const float* __restrict__ rs_out, __half* __restrict__ y, int N) {
  int tid = threadIdx.x;
  int wave = tid >> 6, lane = tid & 63;
  int bt = blockIdx.y * 4 + wave;     // 0..7
  int b = bt >> 2, t = bt & 3;
  int fh = blockIdx.z * 32;           // f half: 0 or 32
  int n = blockIdx.x * 64 + lane;

  const float* xp = in_feat + (size_t)(b * 256 + t) * (size_t)N;  // h=0 row
  size_t hstride = (size_t)4 * (size_t)N;

  float acc[32];
  #pragma unroll
  for (int f = 0; f < 32; ++f) acc[f] = 0.0f;

  bool ok = (n < N);
  #pragma unroll 4
  for (int h = 0; h < 64; ++h) {
    float xv = ok ? xp[(size_t)h * hstride + n] : 0.0f;
    const float* wrow = W + h * 64 + fh;   // wave-uniform address -> s_load
    #pragma unroll
    for (int f = 0; f < 32; ++f) acc[f] = fmaf(xv, wrow[f], acc[f]);
  }

  if (ok) {
    float rs = rs_out[n];
    union { unsigned int u[16]; uint4 v[4]; } pk;
    #pragma unroll
    for (int q = 0; q < 16; ++q) {
      __half2 h = __float22half2_rn(make_float2(acc[2 * q] * rs, acc[2 * q + 1] * rs));
      pk.u[q] = *(unsigned int*)&h;
    }
    uint4* yp = (uint4*)(y + (size_t)n * 512 + bt * 64 + fh);
    #pragma unroll
    for (int q = 0; q < 4; ++q) yp[q] = pk.v[q];
  }
}

// out[((b*64+f)*4+t)*N + n] = relu( rs_in[n] * sum_{j in CSR(n)} y[csr_src[j]][c] + bias[f] )
// 512 threads = 8 waves; wave handles 2 nodes (16-node tile, 33KB LDS ->
// 4 blocks/CU -> 32 waves/CU). Per node: lane-parallel CSR index block load,
// readlane broadcast, per-edge 2x8B independent loads.
extern "C" __global__ __launch_bounds__(512) void k_aggregate(
    const __half* __restrict__ y, const int* __restrict__ offs,
    const int* __restrict__ csr_src, const float* __restrict__ rs_in,
    const float* __restrict__ bvec, float* __restrict__ out, int N) {
  __shared__ float agg[16 * 513];  // [node][channel], pad -> benign epilogue banks
  int tid = threadIdx.x;
  int lane = tid & 63, wave = tid >> 6;   // 8 waves
  int n0 = blockIdx.x * 16;

#define ACC_EDGE(s)                                                          \
  {                                                                          \
    const uint2* rp = (const uint2*)(y + (size_t)(s) * 512);                 \
    uint2 ua = rp[lane];                                                     \
    uint2 ub = rp[64 + lane];                                                \
    float2 f;                                                                \
    f = __half22float2(*(const __half2*)&ua.x); accA.x += f.x; accA.y += f.y;\
    f = __half22float2(*(const __half2*)&ua.y); accA.z += f.x; accA.w += f.y;\
    f = __half22float2(*(const __half2*)&ub.x); accB.x += f.x; accB.y += f.y;\
    f = __half22float2(*(const __half2*)&ub.y); accB.z += f.x; accB.w += f.y;\
  }

  #pragma unroll
  for (int k = 0; k < 2; ++k) {
    int nl = k * 8 + wave;
    int n = n0 + nl;
    float4 accA = {0.f, 0.f, 0.f, 0.f};
    float4 accB = {0.f, 0.f, 0.f, 0.f};
    if (n < N) {
      int j0 = offs[n], j1 = offs[n + 1];
      for (int base = j0; base < j1; base += 64) {
        int idxv = csr_src[base + lane];  // coalesced block of up to 64 indices
        int m = j1 - base; if (m > 64) m = 64;
        int e = 0;
        for (; e + 3 < m; e += 4) {
          int s0 = __builtin_amdgcn_readlane(idxv, e);
          int s1 = __builtin_amdgcn_readlane(idxv, e + 1);
          int s2 = __builtin_amdgcn_readlane(idxv, e + 2);
          int s3 = __builtin_amdgcn_readlane(idxv, e + 3);
          ACC_EDGE(s0); ACC_EDGE(s1); ACC_EDGE(s2); ACC_EDGE(s3);
        }
        for (; e < m; ++e) {
          int s0 = __builtin_amdgcn_readlane(idxv, e);
          ACC_EDGE(s0);
        }
      }
    }
    *(float4*)&agg[nl * 513 + lane * 4] = accA;
    *(float4*)&agg[nl * 513 + 256 + lane * 4] = accB;
  }
#undef ACC_EDGE
  __syncthreads();

  // epilogue: scale, bias, relu, transpose-back to channel-major
  int nl = tid & 15;
  int r0 = tid >> 4;  // 0..31
  int n = n0 + nl;
  float rs = (n < N) ? rs_in[n] : 0.0f;
  #pragma unroll 4
  for (int it = 0; it < 16; ++it) {
    int c = it * 32 + r0;          // c = (b*4+t)*64 + f
    float v = agg[nl * 513 + c];
    int f = c & 63, bt = c >> 6;
    int b = bt >> 2, t = bt & 3;
    v = v * rs + bvec[f];
    v = fmaxf(v, 0.0f);
    if (n < N) out[(size_t)((b * 64 + f) * 4 + t) * (size_t)N + n] = v;
  }
}

extern "C" void kernel_launch(void* const* d_in, const int* in_sizes, int n_in,
                              void* d_out, int out_size, void* d_ws, size_t ws_size,
                              hipStream_t stream) {
  const float* in_feat = (const float*)d_in[0];
  const int*   src     = (const int*)d_in[1];
  const int*   dst     = (const int*)d_in[2];
  const float* W       = (const float*)d_in[3];
  const float* bvec    = (const float*)d_in[4];
  float* out = (float*)d_out;

  int N = in_sizes[0] / 512;   // B*H*T = 2*64*4 = 512
  int E = in_sizes[1];

  int A  = (N + 64) & ~63;     // room for N+1 offsets, 64-aligned
  int EA = (E + 63) & ~63;
  int M  = (N + 255) / 256;    // scan blocks (<= 256 for N <= 65536)

  // layout: the three arrays needing zero-init come first (one contiguous memset)
  int*   deg_out_i = (int*)d_ws;        // [A]  zeroed
  int*   deg_in_i  = deg_out_i + A;     // [A]  zeroed
  int*   cursor    = deg_in_i + A;      // [A]  zeroed
  int*   offs      = cursor + A;        // [A] (N+1 used, fully written by scans)
  int*   bsum      = offs + A;          // [256]
  int*   boffs     = bsum + 256;        // [256]
  float* rs_out    = (float*)(boffs + 256);
  float* rs_in     = rs_out + A;
  int*   csr_src   = (int*)(rs_in + A); // [EA] (+slack: y follows, overreads safe)
  __half* y        = (__half*)(csr_src + EA); // [N*512] fp16

  int z = 3 * A;
  hipLaunchKernelGGL(k_zero, dim3((z + 255) / 256), dim3(256), 0, stream, deg_out_i, z);
  hipLaunchKernelGGL(k_deg, dim3((E + 255) / 256), dim3(256), 0, stream,
                     src, dst, deg_out_i, deg_in_i, E);
  hipLaunchKernelGGL(k_rsqrt, dim3((N + 255) / 256), dim3(256), 0, stream,
                     deg_out_i, deg_in_i, rs_out, rs_in, N);
  hipLaunchKernelGGL(k_scan1, dim3(M), dim3(256), 0, stream, deg_in_i, bsum, N);
  hipLaunchKernelGGL(k_scan2, dim3(1), dim3(256), 0, stream, bsum, boffs, offs, M, N);
  hipLaunchKernelGGL(k_scan3, dim3(M), dim3(256), 0, stream, deg_in_i, boffs, offs, N);
  hipLaunchKernelGGL(k_scatter, dim3((E + 255) / 256), dim3(256), 0, stream,
                     src, dst, offs, cursor, csr_src, E);
  hipLaunchKernelGGL(k_transform, dim3((N + 63) / 64, 2, 2), dim3(256), 0, stream,
                     in_feat, W, rs_out, y, N);
  hipLaunchKernelGGL(k_aggregate, dim3((N + 15) / 16), dim3(512), 0, stream,
                     y, offs, csr_src, rs_in, bvec, out, N);
}